// Round 8
// baseline (281.889 us; speedup 1.0000x reference)
//
#include <hip/hip_runtime.h>
#include <math.h>

// B=2, C=O=256, H=W=64, K=33 offsets (D=4 rings).
typedef __attribute__((ext_vector_type(4))) float f4;

__device__ __forceinline__ int iclamp(int x, int lo, int hi) { return min(max(x, lo), hi); }

// k=0:(0,0); rings s=1..4: (-s,-s),(-s,0),(-s,s),(0,-s),(0,s),(s,-s),(s,0),(s,s)
__device__ constexpr int DXC[33] = {0, -1,-1,-1,0,0,1,1,1, -2,-2,-2,0,0,2,2,2, -3,-3,-3,0,0,3,3,3, -4,-4,-4,0,0,4,4,4};
__device__ constexpr int DYC[33] = {0, -1,0,1,-1,1,-1,0,1, -2,0,2,-2,2,-2,0,2, -3,0,3,-3,3,-3,0,3, -4,0,4,-4,4,-4,0,4};

// ---------------------------------------------------------------------------
// GEMM v3: E[b][o][p] = sum_c W[o][c]*X[b][c][p] + bias[o]
// 128(o) x 128(p) tile, 8x8 acc/thread -> 4 ds_read_b128 per 64 FMA (LDS ~=
// VALU, balanced). B columns split tn*4 / 64+tn*4 -> 2-way LDS conflict (free).
// K-chunk 16, reg->LDS dbuf, 1 barrier/chunk. Grid (32,2,4)=256 blocks (1/CU).
// ---------------------------------------------------------------------------
__global__ __launch_bounds__(256, 2) void gemm_f32(
    const float* __restrict__ Wf, const float* __restrict__ bf,
    const float* __restrict__ Wg, const float* __restrict__ bg,
    const float* __restrict__ Ft, const float* __restrict__ FtE,
    float* __restrict__ Ef, float* __restrict__ Eg)
{
    __shared__ float As[2][16][132];   // [c][o] transposed, pad 132
    __shared__ float Bs[2][16][128];   // [c][p]

    const int gb = blockIdx.z;
    const int g = gb >> 1, b = gb & 1;
    const float* Wmat = g ? Wg : Wf;
    const float* bias = g ? bg : bf;
    const float* X = (g ? FtE : Ft) + (size_t)b * 256 * 4096;
    float* E = (g ? Eg : Ef) + (size_t)b * 256 * 4096;

    const int tid = threadIdx.x;
    const int tn = tid & 15, tm = tid >> 4;
    const int m0 = blockIdx.y * 128, n0 = blockIdx.x * 128;

    float acc[8][8] = {};
    f4 areg[2], breg[2];

    auto loadG = [&](int kk) {
        #pragma unroll
        for (int i = 0; i < 2; ++i) {
            int f = i * 256 + tid;
            areg[i] = *(const f4*)&Wmat[(size_t)(m0 + (f >> 2)) * 256 + kk + (f & 3) * 4];
            breg[i] = *(const f4*)&X[(size_t)(kk + (f >> 5)) * 4096 + n0 + (f & 31) * 4];
        }
    };
    auto storeL = [&](int buf) {
        #pragma unroll
        for (int i = 0; i < 2; ++i) {
            int f = i * 256 + tid;
            int o = f >> 2, cq = f & 3;
            As[buf][cq * 4 + 0][o] = areg[i].x;
            As[buf][cq * 4 + 1][o] = areg[i].y;
            As[buf][cq * 4 + 2][o] = areg[i].z;
            As[buf][cq * 4 + 3][o] = areg[i].w;
            *(f4*)&Bs[buf][f >> 5][(f & 31) * 4] = breg[i];
        }
    };

    loadG(0); storeL(0);
    __syncthreads();

    for (int ch = 0; ch < 16; ++ch) {
        const int buf = ch & 1;
        if (ch < 15) loadG((ch + 1) * 16);
        #pragma unroll
        for (int k = 0; k < 16; ++k) {
            f4 a0 = *(const f4*)&As[buf][k][tm * 8];
            f4 a1 = *(const f4*)&As[buf][k][tm * 8 + 4];
            f4 b0 = *(const f4*)&Bs[buf][k][tn * 4];
            f4 b1 = *(const f4*)&Bs[buf][k][64 + tn * 4];
            #pragma unroll
            for (int ii = 0; ii < 4; ++ii)
                #pragma unroll
                for (int jj = 0; jj < 4; ++jj) {
                    acc[ii][jj]         += a0[ii] * b0[jj];
                    acc[ii][4 + jj]     += a0[ii] * b1[jj];
                    acc[4 + ii][jj]     += a1[ii] * b0[jj];
                    acc[4 + ii][4 + jj] += a1[ii] * b1[jj];
                }
        }
        if (ch < 15) storeL(buf ^ 1);
        __syncthreads();
    }

    #pragma unroll
    for (int r = 0; r < 8; ++r) {
        int o = m0 + tm * 8 + r;
        float bvs = bias[o];
        f4 v0 = { acc[r][0] + bvs, acc[r][1] + bvs, acc[r][2] + bvs, acc[r][3] + bvs };
        f4 v1 = { acc[r][4] + bvs, acc[r][5] + bvs, acc[r][6] + bvs, acc[r][7] + bvs };
        *(f4*)&E[(size_t)o * 4096 + n0 + tn * 4] = v0;
        *(f4*)&E[(size_t)o * 4096 + n0 + 64 + tn * 4] = v1;
    }
}

// ---------------------------------------------------------------------------
// aff_part v3: part[cseg][b][k][p] = sum_{c in cseg's 32} Eg[c,p]*Ef[c,p+off_k]
// grid (64 h, 2 b, 8 cseg) = 1024 blocks (4/CU), block 256 = 64 w x 4 kg.
// LDS dbuf [10 rows][4 ch][72 w-halo] = 23 KB; w-halo pre-clamped; k-loop
// row-grouped so same-row reads merge into ds_read2_b32.
// ---------------------------------------------------------------------------
template<int K0, int NK>
__device__ __forceinline__ void aff_acc4(const float* __restrict__ base, float* __restrict__ aff)
{
    #pragma unroll
    for (int ch = 0; ch < 4; ++ch) {
        float eg = base[(36 + ch) * 72];     // d=9 (Eg) row
        #pragma unroll
        for (int j = 0; j < NK; ++j) {
            int k = K0 + j;
            aff[j] += eg * base[((DXC[k] + 4) * 4 + ch) * 72 + DYC[k]];
        }
    }
}

__global__ __launch_bounds__(256, 4) void aff_part(
    const float* __restrict__ Ef, const float* __restrict__ Eg,
    float* __restrict__ part)
{
    __shared__ float L[2][10 * 4 * 72];   // [d][ch][72]

    const int h = blockIdx.x, b = blockIdx.y, cseg = blockIdx.z;
    const int tid = threadIdx.x;
    const int w = tid & 63, kg = tid >> 6;    // kg wave-uniform
    const size_t plane = (size_t)b * 256 * 4096;
    const float* EfB = Ef + plane;
    const float* EgB = Eg + plane;
    const int cbase = cseg * 32;

    int hr[10];
    #pragma unroll
    for (int d = 0; d < 10; ++d) hr[d] = (d < 9) ? iclamp(h + d - 4, 0, 63) : h;

    f4 vreg[3]; float sreg[2];

    auto load_rnd = [&](int r) {
        const int c0 = cbase + r * 4;
        #pragma unroll
        for (int i = 0; i < 3; ++i) {
            int f = i * 256 + tid;
            if (f < 640) {
                int d = f >> 6, rem = f & 63, ch = rem >> 4, c4 = rem & 15;
                const float* src = (d < 9) ? EfB : EgB;
                vreg[i] = *(const f4*)&src[(size_t)(c0 + ch) * 4096 + hr[d] * 64 + c4 * 4];
            }
        }
        #pragma unroll
        for (int i = 0; i < 2; ++i) {
            int e = i * 256 + tid;
            if (e < 320) {
                int row = e >> 3, sc = e & 7, d = row >> 2, ch = row & 3;
                int wsrc = (sc < 4) ? 0 : 63;
                const float* src = (d < 9) ? EfB : EgB;
                sreg[i] = src[(size_t)(c0 + ch) * 4096 + hr[d] * 64 + wsrc];
            }
        }
    };
    auto store_rnd = [&](int buf) {
        float* Lb = L[buf];
        #pragma unroll
        for (int i = 0; i < 3; ++i) {
            int f = i * 256 + tid;
            if (f < 640) {
                int d = f >> 6, rem = f & 63, ch = rem >> 4, c4 = rem & 15;
                *(f4*)&Lb[(d * 4 + ch) * 72 + 4 + c4 * 4] = vreg[i];
            }
        }
        #pragma unroll
        for (int i = 0; i < 2; ++i) {
            int e = i * 256 + tid;
            if (e < 320) {
                int row = e >> 3, sc = e & 7, d = row >> 2, ch = row & 3;
                int col = (sc < 4) ? sc : (64 + sc);
                Lb[(d * 4 + ch) * 72 + col] = sreg[i];
            }
        }
    };

    float aff[9] = {0.f,0.f,0.f,0.f,0.f,0.f,0.f,0.f,0.f};

    load_rnd(0); store_rnd(0);
    for (int r = 0; r < 8; ++r) {             // 32 ch / 4 per round
        if (r < 7) load_rnd(r + 1);
        __syncthreads();
        const float* base = &L[r & 1][4 + w];
        switch (kg) {                          // wave-uniform branch
            case 0: aff_acc4<0, 9>(base, aff); break;
            case 1: aff_acc4<9, 8>(base, aff); break;
            case 2: aff_acc4<17, 8>(base, aff); break;
            default: aff_acc4<25, 8>(base, aff); break;
        }
        if (r < 7) store_rnd((r + 1) & 1);
    }

    const int k0 = (kg == 0) ? 0 : (kg == 1) ? 9 : (kg == 2) ? 17 : 25;
    const int nk = (kg == 0) ? 9 : 8;
    float* pB = part + (((size_t)cseg * 2 + b) * 33) * 4096 + h * 64 + w;
    for (int j = 0; j < nk; ++j) pB[(size_t)(k0 + j) * 4096] = aff[j];
}

// ---------------------------------------------------------------------------
// softmax_k: per pixel sum 8 partials, mask invalid -> -inf, softmax, write
// wgt[b][k][p]. 128 blocks x 64 (spread over 128 CUs, coalesced loads).
// ---------------------------------------------------------------------------
__global__ __launch_bounds__(64) void softmax_k(
    const float* __restrict__ part, float* __restrict__ wgt)
{
    const int id = blockIdx.x * 64 + threadIdx.x;
    const int b = id >> 12, p = id & 4095;
    const int h = p >> 6, w = p & 63;

    float a[33];
    float m = -INFINITY;
    #pragma unroll
    for (int k = 0; k < 33; ++k) {
        float s = 0.f;
        #pragma unroll
        for (int seg = 0; seg < 8; ++seg)
            s += part[(((size_t)seg * 2 + b) * 33 + k) * 4096 + p];
        bool valid = ((unsigned)(h + DXC[k]) < 64u) && ((unsigned)(w + DYC[k]) < 64u);
        a[k] = valid ? s : -INFINITY;
        m = fmaxf(m, a[k]);
    }
    float ssum = 0.f;
    #pragma unroll
    for (int k = 0; k < 33; ++k) { float e = __expf(a[k] - m); a[k] = e; ssum += e; }
    float inv = 1.0f / ssum;
    float* wgtB = wgt + (size_t)b * 33 * 4096 + p;
    #pragma unroll
    for (int k = 0; k < 33; ++k) wgtB[(size_t)k * 4096] = a[k] * inv;
}

// ---------------------------------------------------------------------------
// out v3: out[c][p] = sum_k wgt[k,p]*Ft[c,p+off_k].
// grid (64 h, 2 b, 8 cseg) = 1024 blocks (4/CU), block 256 = 64 w x 4 cg
// (1 ch per cg per 4-ch round). LDS dbuf [9][4][72] = 20.7 KB. wv[33] in regs.
// Invalid k has wgt==0 -> clamped gather contributes 0.
// ---------------------------------------------------------------------------
__global__ __launch_bounds__(256, 4) void out_kernel(
    const float* __restrict__ wgt, const float* __restrict__ Ft,
    float* __restrict__ out)
{
    __shared__ float L[2][9 * 4 * 72];

    const int h = blockIdx.x, b = blockIdx.y, cseg = blockIdx.z;
    const int tid = threadIdx.x;
    const int w = tid & 63, cg = tid >> 6;    // cg wave-uniform
    const size_t plane = (size_t)b * 256 * 4096;
    const float* FtB = Ft + plane;
    float* outB = out + plane;
    const int cbase = cseg * 32;
    const int p = h * 64 + w;

    const float* wgtB = wgt + (size_t)b * 33 * 4096 + p;
    float wv[33];
    #pragma unroll
    for (int k = 0; k < 33; ++k) wv[k] = wgtB[(size_t)k * 4096];

    int hr[9];
    #pragma unroll
    for (int d = 0; d < 9; ++d) hr[d] = iclamp(h + d - 4, 0, 63);

    f4 vreg[3]; float sreg[2];

    auto load_rnd = [&](int r) {
        const int c0 = cbase + r * 4;
        #pragma unroll
        for (int i = 0; i < 3; ++i) {
            int f = i * 256 + tid;
            if (f < 576) {
                int d = f >> 6, rem = f & 63, ch = rem >> 4, c4 = rem & 15;
                vreg[i] = *(const f4*)&FtB[(size_t)(c0 + ch) * 4096 + hr[d] * 64 + c4 * 4];
            }
        }
        #pragma unroll
        for (int i = 0; i < 2; ++i) {
            int e = i * 256 + tid;
            if (e < 288) {
                int row = e >> 3, sc = e & 7, d = row >> 2, ch = row & 3;
                int wsrc = (sc < 4) ? 0 : 63;
                sreg[i] = FtB[(size_t)(c0 + ch) * 4096 + hr[d] * 64 + wsrc];
            }
        }
    };
    auto store_rnd = [&](int buf) {
        float* Lb = L[buf];
        #pragma unroll
        for (int i = 0; i < 3; ++i) {
            int f = i * 256 + tid;
            if (f < 576) {
                int d = f >> 6, rem = f & 63, ch = rem >> 4, c4 = rem & 15;
                *(f4*)&Lb[(d * 4 + ch) * 72 + 4 + c4 * 4] = vreg[i];
            }
        }
        #pragma unroll
        for (int i = 0; i < 2; ++i) {
            int e = i * 256 + tid;
            if (e < 288) {
                int row = e >> 3, sc = e & 7, d = row >> 2, ch = row & 3;
                int col = (sc < 4) ? sc : (64 + sc);
                Lb[(d * 4 + ch) * 72 + col] = sreg[i];
            }
        }
    };

    load_rnd(0); store_rnd(0);
    for (int r = 0; r < 8; ++r) {             // 32 ch / 4 per round
        if (r < 7) load_rnd(r + 1);
        __syncthreads();
        const float* base = &L[r & 1][4 + w];
        float o = 0.f;
        #pragma unroll
        for (int k = 0; k < 33; ++k)
            o += wv[k] * base[((DXC[k] + 4) * 4 + cg) * 72 + DYC[k]];
        int c = cbase + r * 4 + cg;
        outB[(size_t)c * 4096 + p] = o;
        if (r < 7) store_rnd((r + 1) & 1);
    }
}

// ---------------------------------------------------------------------------
extern "C" void kernel_launch(void* const* d_in, const int* in_sizes, int n_in,
                              void* d_out, int out_size, void* d_ws, size_t ws_size,
                              hipStream_t stream) {
    const float* Ft  = (const float*)d_in[0];
    const float* FtE = (const float*)d_in[1];
    const float* Wf  = (const float*)d_in[2];
    const float* bf  = (const float*)d_in[3];
    const float* Wg  = (const float*)d_in[4];
    const float* bg  = (const float*)d_in[5];
    float* out = (float*)d_out;

    // ws: Ef 8.4MB | Eg 8.4MB | part [8][2][33][4096] 8.7MB | wgt 1.1MB
    float* Ef  = (float*)d_ws;
    float* Eg  = Ef + (size_t)2 * 256 * 4096;
    float* part = Eg + (size_t)2 * 256 * 4096;
    float* wgt = part + (size_t)8 * 2 * 33 * 4096;

    hipLaunchKernelGGL(gemm_f32, dim3(32, 2, 4), dim3(256), 0, stream,
                       Wf, bf, Wg, bg, Ft, FtE, Ef, Eg);
    hipLaunchKernelGGL(aff_part, dim3(64, 2, 8), dim3(256), 0, stream,
                       Ef, Eg, part);
    hipLaunchKernelGGL(softmax_k, dim3(128), dim3(64), 0, stream,
                       part, wgt);
    hipLaunchKernelGGL(out_kernel, dim3(64, 2, 8), dim3(256), 0, stream,
                       wgt, Ft, out);
}

// Round 10
// 204.659 us; speedup vs baseline: 1.3774x; 1.3774x over previous
//
#include <hip/hip_runtime.h>
#include <math.h>

// B=2, C=O=256, H=W=64, K=33 offsets (D=4 rings).
typedef __attribute__((ext_vector_type(4))) float f4;

__device__ __forceinline__ int iclamp(int x, int lo, int hi) { return min(max(x, lo), hi); }

// Offsets sorted row-major (dx, then dy) so same-row stencil reads are
// adjacent -> ds_read2_b32 pairable. Permutation is consistent across
// aff / softmax-mask / out, so softmax result is unchanged.
__device__ constexpr int DXS[33] = {-4,-4,-4, -3,-3,-3, -2,-2,-2, -1,-1,-1,
                                     0,0,0,0,0,0,0,0,0,
                                     1,1,1, 2,2,2, 3,3,3, 4,4,4};
__device__ constexpr int DYS[33] = {-4,0,4, -3,0,3, -2,0,2, -1,0,1,
                                    -4,-3,-2,-1,0,1,2,3,4,
                                    -1,0,1, -2,0,2, -3,0,3, -4,0,4};

// ---------------------------------------------------------------------------
// GEMM v3 (spill-fixed): E[b][o][p] = sum_c W[o][c]*X[b][c][p] + bias[o]
// 128x128 tile, 8x8 acc/thread. (256,1): VGPR cap 512 -> allocator stops
// targeting the 128 notch that caused R8's 458 MB scratch spill.
// ---------------------------------------------------------------------------
__global__ __launch_bounds__(256, 1) void gemm_f32(
    const float* __restrict__ Wf, const float* __restrict__ bf,
    const float* __restrict__ Wg, const float* __restrict__ bg,
    const float* __restrict__ Ft, const float* __restrict__ FtE,
    float* __restrict__ Ef, float* __restrict__ Eg)
{
    __shared__ float As[2][16][132];   // [c][o] transposed, pad 132
    __shared__ float Bs[2][16][128];   // [c][p]

    const int gb = blockIdx.z;
    const int g = gb >> 1, b = gb & 1;
    const float* Wmat = g ? Wg : Wf;
    const float* bias = g ? bg : bf;
    const float* X = (g ? FtE : Ft) + (size_t)b * 256 * 4096;
    float* E = (g ? Eg : Ef) + (size_t)b * 256 * 4096;

    const int tid = threadIdx.x;
    const int tn = tid & 15, tm = tid >> 4;
    const int m0 = blockIdx.y * 128, n0 = blockIdx.x * 128;

    float acc[8][8] = {};
    f4 areg[2], breg[2];

    auto loadG = [&](int kk) {
        #pragma unroll
        for (int i = 0; i < 2; ++i) {
            int f = i * 256 + tid;
            areg[i] = *(const f4*)&Wmat[(size_t)(m0 + (f >> 2)) * 256 + kk + (f & 3) * 4];
            breg[i] = *(const f4*)&X[(size_t)(kk + (f >> 5)) * 4096 + n0 + (f & 31) * 4];
        }
    };
    auto storeL = [&](int buf) {
        #pragma unroll
        for (int i = 0; i < 2; ++i) {
            int f = i * 256 + tid;
            int o = f >> 2, cq = f & 3;
            As[buf][cq * 4 + 0][o] = areg[i].x;
            As[buf][cq * 4 + 1][o] = areg[i].y;
            As[buf][cq * 4 + 2][o] = areg[i].z;
            As[buf][cq * 4 + 3][o] = areg[i].w;
            *(f4*)&Bs[buf][f >> 5][(f & 31) * 4] = breg[i];
        }
    };

    loadG(0); storeL(0);
    __syncthreads();

    for (int ch = 0; ch < 16; ++ch) {
        const int buf = ch & 1;
        if (ch < 15) loadG((ch + 1) * 16);
        #pragma unroll
        for (int k = 0; k < 16; ++k) {
            f4 a0 = *(const f4*)&As[buf][k][tm * 8];
            f4 a1 = *(const f4*)&As[buf][k][tm * 8 + 4];
            f4 b0 = *(const f4*)&Bs[buf][k][tn * 4];
            f4 b1 = *(const f4*)&Bs[buf][k][64 + tn * 4];
            #pragma unroll
            for (int ii = 0; ii < 4; ++ii)
                #pragma unroll
                for (int jj = 0; jj < 4; ++jj) {
                    acc[ii][jj]         += a0[ii] * b0[jj];
                    acc[ii][4 + jj]     += a0[ii] * b1[jj];
                    acc[4 + ii][jj]     += a1[ii] * b0[jj];
                    acc[4 + ii][4 + jj] += a1[ii] * b1[jj];
                }
        }
        if (ch < 15) storeL(buf ^ 1);
        __syncthreads();
    }

    #pragma unroll
    for (int r = 0; r < 8; ++r) {
        int o = m0 + tm * 8 + r;
        float bvs = bias[o];
        f4 v0 = { acc[r][0] + bvs, acc[r][1] + bvs, acc[r][2] + bvs, acc[r][3] + bvs };
        f4 v1 = { acc[r][4] + bvs, acc[r][5] + bvs, acc[r][6] + bvs, acc[r][7] + bvs };
        *(f4*)&E[(size_t)o * 4096 + n0 + tn * 4] = v0;
        *(f4*)&E[(size_t)o * 4096 + n0 + 64 + tn * 4] = v1;
    }
}

// ---------------------------------------------------------------------------
// aff_part v4: part[cseg][b][k][p] = sum_{c in cseg's 16} Eg[c,p]*Ef[c,p+off_k]
// 4-row h-strips: halo re-read 3x instead of 9x (84 -> 34 MB staging volume).
// grid (16 strips, 2 b, 16 cseg) = 512 blocks (2/CU), block 256 = 1 px/thread
// (64 w x 4 strip-rows; row wave-uniform). 4 rounds of 4 ch, LDS dbuf 35 KB.
// ---------------------------------------------------------------------------
__global__ __launch_bounds__(256, 4) void aff_part(
    const float* __restrict__ Ef, const float* __restrict__ Eg,
    float* __restrict__ part)
{
    __shared__ float Lef[2][4][12][72];  // [buf][ch][hrow 12=4+8halo][72 w-halo]
    __shared__ float Leg[2][4][4][64];   // [buf][ch][strip row][w]

    const int strip = blockIdx.x, b = blockIdx.y, cseg = blockIdx.z;
    const int h0 = strip * 4, c0 = cseg * 16;
    const int tid = threadIdx.x;
    const int hs = tid >> 6, w = tid & 63;    // hs wave-uniform
    const int h = h0 + hs, p = h * 64 + w;
    const size_t plane = (size_t)b * 256 * 4096;
    const float* EfB = Ef + plane;
    const float* EgB = Eg + plane;

    int hr[12];
    #pragma unroll
    for (int r = 0; r < 12; ++r) hr[r] = iclamp(h0 - 4 + r, 0, 63);

    f4 vef[3], veg; float sed[2];

    auto load_rnd = [&](int rnd) {
        const int c0r = c0 + rnd * 4;
        #pragma unroll
        for (int i = 0; i < 3; ++i) {          // 768 f4 interior
            int idx = i * 256 + tid;
            int ch = idx / 192, rem = idx % 192, rr = rem >> 4, c4 = rem & 15;
            vef[i] = *(const f4*)&EfB[(size_t)(c0r + ch) * 4096 + hr[rr] * 64 + c4 * 4];
        }
        {                                       // 256 f4 Eg strip rows
            int ch = tid >> 6, rem = tid & 63, rr = rem >> 4, c4 = rem & 15;
            veg = *(const f4*)&EgB[(size_t)(c0r + ch) * 4096 + (h0 + rr) * 64 + c4 * 4];
        }
        #pragma unroll
        for (int i = 0; i < 2; ++i) {          // 384 edge scalars
            int e = i * 256 + tid;
            if (e < 384) {
                int row = e >> 3, sc = e & 7, ch = row / 12, rr = row % 12;
                int wsrc = (sc < 4) ? 0 : 63;
                sed[i] = EfB[(size_t)(c0r + ch) * 4096 + hr[rr] * 64 + wsrc];
            }
        }
    };
    auto store_rnd = [&](int buf) {
        #pragma unroll
        for (int i = 0; i < 3; ++i) {
            int idx = i * 256 + tid;
            int ch = idx / 192, rem = idx % 192, rr = rem >> 4, c4 = rem & 15;
            *(f4*)&Lef[buf][ch][rr][4 + c4 * 4] = vef[i];
        }
        {
            int ch = tid >> 6, rem = tid & 63, rr = rem >> 4, c4 = rem & 15;
            *(f4*)&Leg[buf][ch][rr][c4 * 4] = veg;
        }
        #pragma unroll
        for (int i = 0; i < 2; ++i) {
            int e = i * 256 + tid;
            if (e < 384) {
                int row = e >> 3, sc = e & 7, ch = row / 12, rr = row % 12;
                int col = (sc < 4) ? sc : (64 + sc);
                Lef[buf][ch][rr][col] = sed[i];
            }
        }
    };

    float aff[33];
    #pragma unroll
    for (int k = 0; k < 33; ++k) aff[k] = 0.f;

    load_rnd(0); store_rnd(0);
    __syncthreads();
    for (int rnd = 0; rnd < 4; ++rnd) {
        if (rnd < 3) load_rnd(rnd + 1);
        const int buf = rnd & 1;
        #pragma unroll
        for (int ch = 0; ch < 4; ++ch) {
            float eg = Leg[buf][ch][hs][w];
            #pragma unroll
            for (int k = 0; k < 33; ++k)
                aff[k] += eg * Lef[buf][ch][hs + 4 + DXS[k]][4 + w + DYS[k]];
        }
        if (rnd < 3) store_rnd(buf ^ 1);
        __syncthreads();
    }

    float* pB = part + (((size_t)cseg * 2 + b) * 33) * 4096 + p;
    #pragma unroll
    for (int k = 0; k < 33; ++k) pB[(size_t)k * 4096] = aff[k];
}

// ---------------------------------------------------------------------------
// softmax_k: per pixel sum 16 partials, mask invalid -> -inf, softmax, write
// wgt[b][k][p]. 128 blocks x 64.
// ---------------------------------------------------------------------------
__global__ __launch_bounds__(64) void softmax_k(
    const float* __restrict__ part, float* __restrict__ wgt)
{
    const int id = blockIdx.x * 64 + threadIdx.x;
    const int b = id >> 12, p = id & 4095;
    const int h = p >> 6, w = p & 63;

    float a[33];
    float m = -INFINITY;
    #pragma unroll
    for (int k = 0; k < 33; ++k) {
        float s = 0.f;
        #pragma unroll
        for (int seg = 0; seg < 16; ++seg)
            s += part[(((size_t)seg * 2 + b) * 33 + k) * 4096 + p];
        bool valid = ((unsigned)(h + DXS[k]) < 64u) && ((unsigned)(w + DYS[k]) < 64u);
        a[k] = valid ? s : -INFINITY;
        m = fmaxf(m, a[k]);
    }
    float ssum = 0.f;
    #pragma unroll
    for (int k = 0; k < 33; ++k) { float e = __expf(a[k] - m); a[k] = e; ssum += e; }
    float inv = 1.0f / ssum;
    float* wgtB = wgt + (size_t)b * 33 * 4096 + p;
    #pragma unroll
    for (int k = 0; k < 33; ++k) wgtB[(size_t)k * 4096] = a[k] * inv;
}

// ---------------------------------------------------------------------------
// out v4: out[c][p] = sum_k wgt[k,p]*Ft[c,p+off_k]. Same strip skeleton as
// aff_part (no Eg row). grid (16,2,16) = 512 blocks, 1 px/thread, wv[33] regs.
// Invalid k has wgt==0 -> clamped gather contributes 0.
// ---------------------------------------------------------------------------
__global__ __launch_bounds__(256, 4) void out_kernel(
    const float* __restrict__ wgt, const float* __restrict__ Ft,
    float* __restrict__ out)
{
    __shared__ float Lft[2][4][12][72];

    const int strip = blockIdx.x, b = blockIdx.y, cseg = blockIdx.z;
    const int h0 = strip * 4, c0 = cseg * 16;
    const int tid = threadIdx.x;
    const int hs = tid >> 6, w = tid & 63;
    const int h = h0 + hs, p = h * 64 + w;
    const size_t plane = (size_t)b * 256 * 4096;
    const float* FtB = Ft + plane;
    float* outB = out + plane;

    const float* wgtB = wgt + (size_t)b * 33 * 4096 + p;
    float wv[33];
    #pragma unroll
    for (int k = 0; k < 33; ++k) wv[k] = wgtB[(size_t)k * 4096];

    int hr[12];
    #pragma unroll
    for (int r = 0; r < 12; ++r) hr[r] = iclamp(h0 - 4 + r, 0, 63);

    f4 vef[3]; float sed[2];

    auto load_rnd = [&](int rnd) {
        const int c0r = c0 + rnd * 4;
        #pragma unroll
        for (int i = 0; i < 3; ++i) {
            int idx = i * 256 + tid;
            int ch = idx / 192, rem = idx % 192, rr = rem >> 4, c4 = rem & 15;
            vef[i] = *(const f4*)&FtB[(size_t)(c0r + ch) * 4096 + hr[rr] * 64 + c4 * 4];
        }
        #pragma unroll
        for (int i = 0; i < 2; ++i) {
            int e = i * 256 + tid;
            if (e < 384) {
                int row = e >> 3, sc = e & 7, ch = row / 12, rr = row % 12;
                int wsrc = (sc < 4) ? 0 : 63;
                sed[i] = FtB[(size_t)(c0r + ch) * 4096 + hr[rr] * 64 + wsrc];
            }
        }
    };
    auto store_rnd = [&](int buf) {
        #pragma unroll
        for (int i = 0; i < 3; ++i) {
            int idx = i * 256 + tid;
            int ch = idx / 192, rem = idx % 192, rr = rem >> 4, c4 = rem & 15;
            *(f4*)&Lft[buf][ch][rr][4 + c4 * 4] = vef[i];
        }
        #pragma unroll
        for (int i = 0; i < 2; ++i) {
            int e = i * 256 + tid;
            if (e < 384) {
                int row = e >> 3, sc = e & 7, ch = row / 12, rr = row % 12;
                int col = (sc < 4) ? sc : (64 + sc);
                Lft[buf][ch][rr][col] = sed[i];
            }
        }
    };

    load_rnd(0); store_rnd(0);
    __syncthreads();
    for (int rnd = 0; rnd < 4; ++rnd) {
        if (rnd < 3) load_rnd(rnd + 1);
        const int buf = rnd & 1;
        #pragma unroll
        for (int ch = 0; ch < 4; ++ch) {
            float o = 0.f;
            #pragma unroll
            for (int k = 0; k < 33; ++k)
                o += wv[k] * Lft[buf][ch][hs + 4 + DXS[k]][4 + w + DYS[k]];
            outB[(size_t)(c0 + rnd * 4 + ch) * 4096 + p] = o;
        }
        if (rnd < 3) store_rnd(buf ^ 1);
        __syncthreads();
    }
}

// ---------------------------------------------------------------------------
extern "C" void kernel_launch(void* const* d_in, const int* in_sizes, int n_in,
                              void* d_out, int out_size, void* d_ws, size_t ws_size,
                              hipStream_t stream) {
    const float* Ft  = (const float*)d_in[0];
    const float* FtE = (const float*)d_in[1];
    const float* Wf  = (const float*)d_in[2];
    const float* bf  = (const float*)d_in[3];
    const float* Wg  = (const float*)d_in[4];
    const float* bg  = (const float*)d_in[5];
    float* out = (float*)d_out;

    // ws: Ef 8.4MB | Eg 8.4MB | part [16][2][33][4096] 17.3MB | wgt 1.1MB
    float* Ef  = (float*)d_ws;
    float* Eg  = Ef + (size_t)2 * 256 * 4096;
    float* part = Eg + (size_t)2 * 256 * 4096;
    float* wgt = part + (size_t)16 * 2 * 33 * 4096;

    hipLaunchKernelGGL(gemm_f32, dim3(32, 2, 4), dim3(256), 0, stream,
                       Wf, bf, Wg, bg, Ft, FtE, Ef, Eg);
    hipLaunchKernelGGL(aff_part, dim3(16, 2, 16), dim3(256), 0, stream,
                       Ef, Eg, part);
    hipLaunchKernelGGL(softmax_k, dim3(128), dim3(64), 0, stream,
                       part, wgt);
    hipLaunchKernelGGL(out_kernel, dim3(16, 2, 16), dim3(256), 0, stream,
                       wgt, Ft, out);
}

// Round 11
// 152.937 us; speedup vs baseline: 1.8432x; 1.3382x over previous
//
#include <hip/hip_runtime.h>
#include <math.h>

// B=2, C=O=256, H=W=64, K=33 offsets (D=4 rings).
typedef __attribute__((ext_vector_type(4))) float f4;

__device__ __forceinline__ int iclamp(int x, int lo, int hi) { return min(max(x, lo), hi); }

// Offsets sorted row-major (dx, then dy) so same-row stencil reads are
// adjacent -> ds_read2_b32 pairable. Permutation is consistent across
// aff / softmax-mask / out, so softmax result is unchanged.
__device__ constexpr int DXS[33] = {-4,-4,-4, -3,-3,-3, -2,-2,-2, -1,-1,-1,
                                     0,0,0,0,0,0,0,0,0,
                                     1,1,1, 2,2,2, 3,3,3, 4,4,4};
__device__ constexpr int DYS[33] = {-4,0,4, -3,0,3, -2,0,2, -1,0,1,
                                    -4,-3,-2,-1,0,1,2,3,4,
                                    -1,0,1, -2,0,2, -3,0,3, -4,0,4};

// ---------------------------------------------------------------------------
// GEMM: E[b][o][p] = sum_c W[o][c]*X[b][c][p] + bias[o]
// 128x128 tile, 8x8 acc/thread. (256,1): 512-VGPR ceiling -> no 128-notch
// spill (R8: 458 MB scratch writes at VGPR=128).
// ---------------------------------------------------------------------------
__global__ __launch_bounds__(256, 1) void gemm_f32(
    const float* __restrict__ Wf, const float* __restrict__ bf,
    const float* __restrict__ Wg, const float* __restrict__ bg,
    const float* __restrict__ Ft, const float* __restrict__ FtE,
    float* __restrict__ Ef, float* __restrict__ Eg)
{
    __shared__ float As[2][16][132];   // [c][o] transposed, pad 132
    __shared__ float Bs[2][16][128];   // [c][p]

    const int gb = blockIdx.z;
    const int g = gb >> 1, b = gb & 1;
    const float* Wmat = g ? Wg : Wf;
    const float* bias = g ? bg : bf;
    const float* X = (g ? FtE : Ft) + (size_t)b * 256 * 4096;
    float* E = (g ? Eg : Ef) + (size_t)b * 256 * 4096;

    const int tid = threadIdx.x;
    const int tn = tid & 15, tm = tid >> 4;
    const int m0 = blockIdx.y * 128, n0 = blockIdx.x * 128;

    float acc[8][8] = {};
    f4 areg[2], breg[2];

    auto loadG = [&](int kk) {
        #pragma unroll
        for (int i = 0; i < 2; ++i) {
            int f = i * 256 + tid;
            areg[i] = *(const f4*)&Wmat[(size_t)(m0 + (f >> 2)) * 256 + kk + (f & 3) * 4];
            breg[i] = *(const f4*)&X[(size_t)(kk + (f >> 5)) * 4096 + n0 + (f & 31) * 4];
        }
    };
    auto storeL = [&](int buf) {
        #pragma unroll
        for (int i = 0; i < 2; ++i) {
            int f = i * 256 + tid;
            int o = f >> 2, cq = f & 3;
            As[buf][cq * 4 + 0][o] = areg[i].x;
            As[buf][cq * 4 + 1][o] = areg[i].y;
            As[buf][cq * 4 + 2][o] = areg[i].z;
            As[buf][cq * 4 + 3][o] = areg[i].w;
            *(f4*)&Bs[buf][f >> 5][(f & 31) * 4] = breg[i];
        }
    };

    loadG(0); storeL(0);
    __syncthreads();

    for (int ch = 0; ch < 16; ++ch) {
        const int buf = ch & 1;
        if (ch < 15) loadG((ch + 1) * 16);
        #pragma unroll
        for (int k = 0; k < 16; ++k) {
            f4 a0 = *(const f4*)&As[buf][k][tm * 8];
            f4 a1 = *(const f4*)&As[buf][k][tm * 8 + 4];
            f4 b0 = *(const f4*)&Bs[buf][k][tn * 4];
            f4 b1 = *(const f4*)&Bs[buf][k][64 + tn * 4];
            #pragma unroll
            for (int ii = 0; ii < 4; ++ii)
                #pragma unroll
                for (int jj = 0; jj < 4; ++jj) {
                    acc[ii][jj]         += a0[ii] * b0[jj];
                    acc[ii][4 + jj]     += a0[ii] * b1[jj];
                    acc[4 + ii][jj]     += a1[ii] * b0[jj];
                    acc[4 + ii][4 + jj] += a1[ii] * b1[jj];
                }
        }
        if (ch < 15) storeL(buf ^ 1);
        __syncthreads();
    }

    #pragma unroll
    for (int r = 0; r < 8; ++r) {
        int o = m0 + tm * 8 + r;
        float bvs = bias[o];
        f4 v0 = { acc[r][0] + bvs, acc[r][1] + bvs, acc[r][2] + bvs, acc[r][3] + bvs };
        f4 v1 = { acc[r][4] + bvs, acc[r][5] + bvs, acc[r][6] + bvs, acc[r][7] + bvs };
        *(f4*)&E[(size_t)o * 4096 + n0 + tn * 4] = v0;
        *(f4*)&E[(size_t)o * 4096 + n0 + 64 + tn * 4] = v1;
    }
}

// ---------------------------------------------------------------------------
// aff_part: part[cseg][b][k][p] = sum_{c in cseg's 16} Eg[c,p]*Ef[c,p+off_k]
// 4-row h-strips, 1 px/thread, aff[33] in regs. (256,1): 512-VGPR ceiling --
// R10's (256,4) allocated the 64 notch and spilled aff[33] to scratch
// (VALUBusy 3.3%, WRITE 181 MB vs 17 ideal). hr[] array inlined away.
// grid (16 strips, 2 b, 16 cseg) = 512 blocks (2/CU, LDS 35.8 KB).
// ---------------------------------------------------------------------------
__global__ __launch_bounds__(256, 1) void aff_part(
    const float* __restrict__ Ef, const float* __restrict__ Eg,
    float* __restrict__ part)
{
    __shared__ float Lef[2][4][12][72];  // [buf][ch][hrow 12=4+8halo][72 w-halo]
    __shared__ float Leg[2][4][4][64];   // [buf][ch][strip row][w]

    const int strip = blockIdx.x, b = blockIdx.y, cseg = blockIdx.z;
    const int h0 = strip * 4, c0 = cseg * 16;
    const int tid = threadIdx.x;
    const int hs = tid >> 6, w = tid & 63;    // hs wave-uniform
    const int h = h0 + hs, p = h * 64 + w;
    const size_t plane = (size_t)b * 256 * 4096;
    const float* EfB = Ef + plane;
    const float* EgB = Eg + plane;

    f4 vef[3], veg; float sed[2];

    auto load_rnd = [&](int rnd) {
        const int c0r = c0 + rnd * 4;
        #pragma unroll
        for (int i = 0; i < 3; ++i) {          // 768 f4 interior
            int idx = i * 256 + tid;
            int ch = idx / 192, rem = idx % 192, rr = rem >> 4, c4 = rem & 15;
            int hrow = iclamp(h0 - 4 + rr, 0, 63);
            vef[i] = *(const f4*)&EfB[(size_t)(c0r + ch) * 4096 + hrow * 64 + c4 * 4];
        }
        {                                       // 256 f4 Eg strip rows
            int ch = tid >> 6, rem = tid & 63, rr = rem >> 4, c4 = rem & 15;
            veg = *(const f4*)&EgB[(size_t)(c0r + ch) * 4096 + (h0 + rr) * 64 + c4 * 4];
        }
        #pragma unroll
        for (int i = 0; i < 2; ++i) {          // 384 edge scalars
            int e = i * 256 + tid;
            if (e < 384) {
                int row = e >> 3, sc = e & 7, ch = row / 12, rr = row % 12;
                int hrow = iclamp(h0 - 4 + rr, 0, 63);
                int wsrc = (sc < 4) ? 0 : 63;
                sed[i] = EfB[(size_t)(c0r + ch) * 4096 + hrow * 64 + wsrc];
            }
        }
    };
    auto store_rnd = [&](int buf) {
        #pragma unroll
        for (int i = 0; i < 3; ++i) {
            int idx = i * 256 + tid;
            int ch = idx / 192, rem = idx % 192, rr = rem >> 4, c4 = rem & 15;
            *(f4*)&Lef[buf][ch][rr][4 + c4 * 4] = vef[i];
        }
        {
            int ch = tid >> 6, rem = tid & 63, rr = rem >> 4, c4 = rem & 15;
            *(f4*)&Leg[buf][ch][rr][c4 * 4] = veg;
        }
        #pragma unroll
        for (int i = 0; i < 2; ++i) {
            int e = i * 256 + tid;
            if (e < 384) {
                int row = e >> 3, sc = e & 7, ch = row / 12, rr = row % 12;
                int col = (sc < 4) ? sc : (64 + sc);
                Lef[buf][ch][rr][col] = sed[i];
            }
        }
    };

    float aff[33];
    #pragma unroll
    for (int k = 0; k < 33; ++k) aff[k] = 0.f;

    load_rnd(0); store_rnd(0);
    __syncthreads();
    for (int rnd = 0; rnd < 4; ++rnd) {
        if (rnd < 3) load_rnd(rnd + 1);
        const int buf = rnd & 1;
        #pragma unroll
        for (int ch = 0; ch < 4; ++ch) {
            float eg = Leg[buf][ch][hs][w];
            #pragma unroll
            for (int k = 0; k < 33; ++k)
                aff[k] += eg * Lef[buf][ch][hs + 4 + DXS[k]][4 + w + DYS[k]];
        }
        if (rnd < 3) store_rnd(buf ^ 1);
        __syncthreads();
    }

    float* pB = part + (((size_t)cseg * 2 + b) * 33) * 4096 + p;
    #pragma unroll
    for (int k = 0; k < 33; ++k) pB[(size_t)k * 4096] = aff[k];
}

// ---------------------------------------------------------------------------
// softmax_k: per pixel sum 16 partials, mask invalid -> -inf, softmax, write
// wgt[b][k][p]. 128 blocks x 64.
// ---------------------------------------------------------------------------
__global__ __launch_bounds__(64, 1) void softmax_k(
    const float* __restrict__ part, float* __restrict__ wgt)
{
    const int id = blockIdx.x * 64 + threadIdx.x;
    const int b = id >> 12, p = id & 4095;
    const int h = p >> 6, w = p & 63;

    float a[33];
    float m = -INFINITY;
    #pragma unroll
    for (int k = 0; k < 33; ++k) {
        float s = 0.f;
        #pragma unroll
        for (int seg = 0; seg < 16; ++seg)
            s += part[(((size_t)seg * 2 + b) * 33 + k) * 4096 + p];
        bool valid = ((unsigned)(h + DXS[k]) < 64u) && ((unsigned)(w + DYS[k]) < 64u);
        a[k] = valid ? s : -INFINITY;
        m = fmaxf(m, a[k]);
    }
    float ssum = 0.f;
    #pragma unroll
    for (int k = 0; k < 33; ++k) { float e = __expf(a[k] - m); a[k] = e; ssum += e; }
    float inv = 1.0f / ssum;
    float* wgtB = wgt + (size_t)b * 33 * 4096 + p;
    #pragma unroll
    for (int k = 0; k < 33; ++k) wgtB[(size_t)k * 4096] = a[k] * inv;
}

// ---------------------------------------------------------------------------
// out: out[c][p] = sum_k wgt[k,p]*Ft[c,p+off_k]. Same strip skeleton as
// aff_part (no Eg row). (256,1): same spill fix (wv[33] must stay in regs).
// grid (16,2,16) = 512 blocks, 1 px/thread.
// Invalid k has wgt==0 -> clamped gather contributes 0.
// ---------------------------------------------------------------------------
__global__ __launch_bounds__(256, 1) void out_kernel(
    const float* __restrict__ wgt, const float* __restrict__ Ft,
    float* __restrict__ out)
{
    __shared__ float Lft[2][4][12][72];

    const int strip = blockIdx.x, b = blockIdx.y, cseg = blockIdx.z;
    const int h0 = strip * 4, c0 = cseg * 16;
    const int tid = threadIdx.x;
    const int hs = tid >> 6, w = tid & 63;
    const int h = h0 + hs, p = h * 64 + w;
    const size_t plane = (size_t)b * 256 * 4096;
    const float* FtB = Ft + plane;
    float* outB = out + plane;

    const float* wgtB = wgt + (size_t)b * 33 * 4096 + p;
    float wv[33];
    #pragma unroll
    for (int k = 0; k < 33; ++k) wv[k] = wgtB[(size_t)k * 4096];

    f4 vef[3]; float sed[2];

    auto load_rnd = [&](int rnd) {
        const int c0r = c0 + rnd * 4;
        #pragma unroll
        for (int i = 0; i < 3; ++i) {
            int idx = i * 256 + tid;
            int ch = idx / 192, rem = idx % 192, rr = rem >> 4, c4 = rem & 15;
            int hrow = iclamp(h0 - 4 + rr, 0, 63);
            vef[i] = *(const f4*)&FtB[(size_t)(c0r + ch) * 4096 + hrow * 64 + c4 * 4];
        }
        #pragma unroll
        for (int i = 0; i < 2; ++i) {
            int e = i * 256 + tid;
            if (e < 384) {
                int row = e >> 3, sc = e & 7, ch = row / 12, rr = row % 12;
                int hrow = iclamp(h0 - 4 + rr, 0, 63);
                int wsrc = (sc < 4) ? 0 : 63;
                sed[i] = FtB[(size_t)(c0r + ch) * 4096 + hrow * 64 + wsrc];
            }
        }
    };
    auto store_rnd = [&](int buf) {
        #pragma unroll
        for (int i = 0; i < 3; ++i) {
            int idx = i * 256 + tid;
            int ch = idx / 192, rem = idx % 192, rr = rem >> 4, c4 = rem & 15;
            *(f4*)&Lft[buf][ch][rr][4 + c4 * 4] = vef[i];
        }
        #pragma unroll
        for (int i = 0; i < 2; ++i) {
            int e = i * 256 + tid;
            if (e < 384) {
                int row = e >> 3, sc = e & 7, ch = row / 12, rr = row % 12;
                int col = (sc < 4) ? sc : (64 + sc);
                Lft[buf][ch][rr][col] = sed[i];
            }
        }
    };

    load_rnd(0); store_rnd(0);
    __syncthreads();
    for (int rnd = 0; rnd < 4; ++rnd) {
        if (rnd < 3) load_rnd(rnd + 1);
        const int buf = rnd & 1;
        #pragma unroll
        for (int ch = 0; ch < 4; ++ch) {
            float o = 0.f;
            #pragma unroll
            for (int k = 0; k < 33; ++k)
                o += wv[k] * Lft[buf][ch][hs + 4 + DXS[k]][4 + w + DYS[k]];
            outB[(size_t)(c0 + rnd * 4 + ch) * 4096 + p] = o;
        }
        if (rnd < 3) store_rnd(buf ^ 1);
        __syncthreads();
    }
}

// ---------------------------------------------------------------------------
extern "C" void kernel_launch(void* const* d_in, const int* in_sizes, int n_in,
                              void* d_out, int out_size, void* d_ws, size_t ws_size,
                              hipStream_t stream) {
    const float* Ft  = (const float*)d_in[0];
    const float* FtE = (const float*)d_in[1];
    const float* Wf  = (const float*)d_in[2];
    const float* bf  = (const float*)d_in[3];
    const float* Wg  = (const float*)d_in[4];
    const float* bg  = (const float*)d_in[5];
    float* out = (float*)d_out;

    // ws: Ef 8.4MB | Eg 8.4MB | part [16][2][33][4096] 17.3MB | wgt 1.1MB
    float* Ef  = (float*)d_ws;
    float* Eg  = Ef + (size_t)2 * 256 * 4096;
    float* part = Eg + (size_t)2 * 256 * 4096;
    float* wgt = part + (size_t)16 * 2 * 33 * 4096;

    hipLaunchKernelGGL(gemm_f32, dim3(32, 2, 4), dim3(256), 0, stream,
                       Wf, bf, Wg, bg, Ft, FtE, Ef, Eg);
    hipLaunchKernelGGL(aff_part, dim3(16, 2, 16), dim3(256), 0, stream,
                       Ef, Eg, part);
    hipLaunchKernelGGL(softmax_k, dim3(128), dim3(64), 0, stream,
                       part, wgt);
    hipLaunchKernelGGL(out_kernel, dim3(16, 2, 16), dim3(256), 0, stream,
                       wgt, Ft, out);
}